// Round 2
// baseline (378.616 us; speedup 1.0000x reference)
//
#include <hip/hip_runtime.h>
#include <hip/hip_bf16.h>
#include <math.h>

#define SEQ 512
#define DM  256
#define NH  8

typedef __attribute__((ext_vector_type(4))) float  f32x4;
typedef __attribute__((ext_vector_type(8))) __bf16 bf16x8;
typedef __attribute__((ext_vector_type(8))) short  s16x8;

__device__ __forceinline__ unsigned short f2bf(float f) {
  unsigned int u = __builtin_bit_cast(unsigned int, f);
  u += 0x7fffu + ((u >> 16) & 1u);           // round-to-nearest-even
  return (unsigned short)(u >> 16);
}
__device__ __forceinline__ float bf2f(unsigned short h) {
  unsigned int u = ((unsigned int)h) << 16;
  return __builtin_bit_cast(float, u);
}
// async global->LDS, 16B per lane; LDS dest is WAVE-UNIFORM base (+lane*16 by HW)
__device__ __forceinline__ void gll16(const void* g, void* ldsbase) {
  __builtin_amdgcn_global_load_lds((const __attribute__((address_space(1))) void*)g,
                                   (__attribute__((address_space(3))) void*)ldsbase,
                                   16, 0, 0);
}

// ---------------------------------------------------------------------------
// kconv: f32 -> bf16 streaming convert (grid*256*32 elements, exact)
__global__ __launch_bounds__(256) void kconv(const float* __restrict__ src,
                                             unsigned short* __restrict__ dst) {
  size_t base = ((size_t)blockIdx.x * 256 + threadIdx.x) * 32;
  #pragma unroll
  for (int u = 0; u < 4; u++) {
    float4 a = *(const float4*)(src + base + u * 8);
    float4 b = *(const float4*)(src + base + u * 8 + 4);
    s16x8 o;
    o[0]=f2bf(a.x); o[1]=f2bf(a.y); o[2]=f2bf(a.z); o[3]=f2bf(a.w);
    o[4]=f2bf(b.x); o[5]=f2bf(b.y); o[6]=f2bf(b.z); o[7]=f2bf(b.w);
    *(s16x8*)(dst + base + u * 8) = o;
  }
}

// ---------------------------------------------------------------------------
// K0: blocks 0..31 convert k (f32->bf16); blocks 32..63 transpose v -> vT bf16
__global__ __launch_bounds__(256) void k0_convert(const float* __restrict__ kin,
                                                  const float* __restrict__ vin,
                                                  unsigned short* __restrict__ kbf,
                                                  unsigned short* __restrict__ vT) {
  __shared__ unsigned short tl[64][72];
  int b = blockIdx.x, t = threadIdx.x;
  if (b < 32) {
    int base = b * 4096 + t * 16;
    float4 a0 = *(const float4*)(kin + base);
    float4 a1 = *(const float4*)(kin + base + 4);
    float4 a2 = *(const float4*)(kin + base + 8);
    float4 a3 = *(const float4*)(kin + base + 12);
    s16x8 o0, o1;
    o0[0]=f2bf(a0.x); o0[1]=f2bf(a0.y); o0[2]=f2bf(a0.z); o0[3]=f2bf(a0.w);
    o0[4]=f2bf(a1.x); o0[5]=f2bf(a1.y); o0[6]=f2bf(a1.z); o0[7]=f2bf(a1.w);
    o1[0]=f2bf(a2.x); o1[1]=f2bf(a2.y); o1[2]=f2bf(a2.z); o1[3]=f2bf(a2.w);
    o1[4]=f2bf(a3.x); o1[5]=f2bf(a3.y); o1[6]=f2bf(a3.z); o1[7]=f2bf(a3.w);
    *(s16x8*)(kbf + base)     = o0;
    *(s16x8*)(kbf + base + 8) = o1;
  } else {
    int tb = b - 32;
    int i0 = (tb >> 2) * 64;
    int m0 = (tb & 3) * 64;
    int r = t >> 2, cq = t & 3;
    #pragma unroll
    for (int u = 0; u < 4; u++) {
      float4 x = *(const float4*)(vin + (size_t)(i0 + r) * DM + m0 + cq * 16 + u * 4);
      tl[cq*16 + u*4 + 0][r] = f2bf(x.x);
      tl[cq*16 + u*4 + 1][r] = f2bf(x.y);
      tl[cq*16 + u*4 + 2][r] = f2bf(x.z);
      tl[cq*16 + u*4 + 3][r] = f2bf(x.w);
    }
    __syncthreads();
    int mm = t >> 2;
    s16x8 w0, w1;
    #pragma unroll
    for (int e = 0; e < 8; e++) { w0[e] = tl[mm][cq*16 + e]; w1[e] = tl[mm][cq*16 + 8 + e]; }
    *(s16x8*)(vT + (size_t)(m0 + mm) * SEQ + i0 + cq * 16)     = w0;
    *(s16x8*)(vT + (size_t)(m0 + mm) * SEQ + i0 + cq * 16 + 8) = w1;
  }
}

// ---------------------------------------------------------------------------
// K1: qp = q @ Wq^T  (f32 out only)
__global__ __launch_bounds__(256) void k1_qproj(const float* __restrict__ q,
                                                const float* __restrict__ Wq,
                                                float* __restrict__ qpf) {
  __shared__ __align__(16) float qrow[DM];
  int i = blockIdx.x, t = threadIdx.x;
  if (t < 64) *(float4*)&qrow[t*4] = *(const float4*)(q + (size_t)i * DM + t * 4);
  __syncthreads();
  int w = t >> 6, lane = t & 63;
  for (int jj = 0; jj < 64; jj++) {
    int j = w * 64 + jj;
    float4 wv = *(const float4*)(Wq + (size_t)j * DM + lane * 4);
    float s = wv.x*qrow[lane*4] + wv.y*qrow[lane*4+1] + wv.z*qrow[lane*4+2] + wv.w*qrow[lane*4+3];
    #pragma unroll
    for (int off = 32; off; off >>= 1) s += __shfl_xor(s, off);
    if (lane == 0) qpf[(size_t)i*DM + j] = s;
  }
}

// ---------------------------------------------------------------------------
// ka_gemm: a[n,i,b] += sum over K-chunk of (qp[i,jcol]*qp[i,m]) * Wkb[(jcol,b),m]
// BM=128(i) x BN=128(b), BK=64 (one j per kstep, 64 m). grid=512 blocks:
// lid = kchunk(8) | head(8) | ntile(2) | mtile(4), XCD-chunk swizzled.
__global__ __launch_bounds__(256) void ka_gemm(const unsigned short* __restrict__ Wkb,
                                               const float* __restrict__ qpf,
                                               float* __restrict__ af) {
  __shared__ __align__(16) unsigned short lA[128 * 72];
  __shared__ __align__(16) unsigned short lB[128 * 64];
  int bid = blockIdx.x;
  int lid = (bid & 7) * 64 + (bid >> 3);          // bijective: 512 % 8 == 0
  int mtile = lid & 3, ntile = (lid >> 2) & 1, head = (lid >> 3) & 7, kchunk = lid >> 6;
  int m0 = mtile * 128, n0 = ntile * 128;
  int t = threadIdx.x, w = t >> 6, lane = t & 63;
  int wr = w >> 1, wc = w & 1;
  f32x4 acc[4][4] = {};

  for (int ks = 0; ks < 16; ks++) {
    int kt = kchunk * 1024 + ks * 64;
    int jcol = head * 32 + (kt >> 8);             // kt>>8 in [0,32)
    int mbase = kt & 255;
    __syncthreads();                              // lB/lA reads of prev iter done
    // B tile via global_load_lds, inverse-swizzled source (rule #21)
    {
      const unsigned short* Bbase = Wkb + ((size_t)jcol * 256 + n0) * 256 + mbase;
      #pragma unroll
      for (int it = 0; it < 4; it++) {
        int r0 = (w * 4 + it) * 8 + (lane >> 3);
        int cbyte = ((lane & 7) * 16) ^ ((r0 & 7) << 4);
        gll16((const char*)(Bbase + (size_t)r0 * 256) + cbyte,
              (char*)lB + (w * 4 + it) * 1024);
      }
    }
    // A tile: product qp[i,jcol]*qp[i,m], reg-staged, pad-72 LDS
    #pragma unroll
    for (int rep = 0; rep < 4; rep++) {
      int sc = rep * 256 + t;
      int row = sc >> 3, c8 = sc & 7;
      int i = m0 + row;
      float scal = qpf[(size_t)i * 256 + jcol];
      const float* src = qpf + (size_t)i * 256 + mbase + c8 * 8;
      float4 u0 = *(const float4*)src, u1 = *(const float4*)(src + 4);
      s16x8 o;
      o[0]=f2bf(scal*u0.x); o[1]=f2bf(scal*u0.y); o[2]=f2bf(scal*u0.z); o[3]=f2bf(scal*u0.w);
      o[4]=f2bf(scal*u1.x); o[5]=f2bf(scal*u1.y); o[6]=f2bf(scal*u1.z); o[7]=f2bf(scal*u1.w);
      *(s16x8*)&lA[row * 72 + c8 * 8] = o;
    }
    __syncthreads();                              // drains vmcnt (gll) + lgkm
    #pragma unroll
    for (int kk = 0; kk < 2; kk++) {
      int r = lane & 15, kc = kk * 32 + (lane >> 4) * 8;
      bf16x8 afr[4], bfr[4];
      #pragma unroll
      for (int mf = 0; mf < 4; mf++) afr[mf] = *(const bf16x8*)&lA[(wr*64 + mf*16 + r) * 72 + kc];
      #pragma unroll
      for (int nf = 0; nf < 4; nf++) {
        int row = wc*64 + nf*16 + r;
        int cb = (kc * 2) ^ ((row & 7) << 4);
        bfr[nf] = *(const bf16x8*)((const char*)lB + row * 128 + cb);
      }
      #pragma unroll
      for (int mf = 0; mf < 4; mf++)
        #pragma unroll
        for (int nf = 0; nf < 4; nf++)
          acc[mf][nf] = __builtin_amdgcn_mfma_f32_16x16x32_bf16(afr[mf], bfr[nf], acc[mf][nf], 0, 0, 0);
    }
  }
  int cr = (lane >> 4) * 4, cc = lane & 15;
  #pragma unroll
  for (int mf = 0; mf < 4; mf++)
    #pragma unroll
    for (int nf = 0; nf < 4; nf++)
      #pragma unroll
      for (int qq = 0; qq < 4; qq++) {
        int i   = m0 + wr*64 + mf*16 + cr + qq;
        int col = n0 + wc*64 + nf*16 + cc;
        atomicAdd(&af[((size_t)head * SEQ + i) * 256 + col], acc[mf][nf][qq]);
      }
}

// ---------------------------------------------------------------------------
// ko_gemm: out[i, head*32+j] += sum over K-chunk of (w[n,i,b]*qp[i,m]) * Wvb[(j,b),m]
// BM=128(i) x BN=32(j), BK=64 (one b per kstep). grid=512:
// lid = kchunk(16) | head(8) | mtile(4), XCD-chunk swizzled.
__global__ __launch_bounds__(256) void ko_gemm(const unsigned short* __restrict__ Wvb,
                                               const float* __restrict__ qpf,
                                               const unsigned short* __restrict__ wbf,
                                               float* __restrict__ out) {
  __shared__ __align__(16) unsigned short lA[128 * 72];
  __shared__ __align__(16) unsigned short lB[32 * 64];
  int bid = blockIdx.x;
  int lid = (bid & 7) * 64 + (bid >> 3);
  int mtile = lid & 3, head = (lid >> 2) & 7, kchunk = lid >> 5;   // 0..15
  int m0 = mtile * 128;
  int t = threadIdx.x, w = t >> 6, lane = t & 63;
  f32x4 acc[2][2] = {};

  for (int ks = 0; ks < 64; ks++) {
    int kt = kchunk * 4096 + ks * 64;
    int kdim = kt >> 8;                            // b in [0,256)
    int mbase = kt & 255;
    __syncthreads();
    // B tile (32 x 64) via gll: one instr per wave
    {
      int r0 = w * 8 + (lane >> 3);
      int cbyte = ((lane & 7) * 16) ^ ((r0 & 7) << 4);
      const unsigned short* Bb = Wvb + (((size_t)head * 32 + r0) * 256 + kdim) * 256 + mbase;
      gll16((const char*)Bb + cbyte, (char*)lB + w * 1024);
    }
    // A tile: w[head,i,kdim] * qp[i,m]
    #pragma unroll
    for (int rep = 0; rep < 4; rep++) {
      int sc = rep * 256 + t;
      int row = sc >> 3, c8 = sc & 7;
      int i = m0 + row;
      float scal = bf2f(wbf[((size_t)head * SEQ + i) * 256 + kdim]);
      const float* src = qpf + (size_t)i * 256 + mbase + c8 * 8;
      float4 u0 = *(const float4*)src, u1 = *(const float4*)(src + 4);
      s16x8 o;
      o[0]=f2bf(scal*u0.x); o[1]=f2bf(scal*u0.y); o[2]=f2bf(scal*u0.z); o[3]=f2bf(scal*u0.w);
      o[4]=f2bf(scal*u1.x); o[5]=f2bf(scal*u1.y); o[6]=f2bf(scal*u1.z); o[7]=f2bf(scal*u1.w);
      *(s16x8*)&lA[row * 72 + c8 * 8] = o;
    }
    __syncthreads();
    #pragma unroll
    for (int kk = 0; kk < 2; kk++) {
      int r = lane & 15, kc = kk * 32 + (lane >> 4) * 8;
      bf16x8 afr[2], bfr[2];
      #pragma unroll
      for (int mf = 0; mf < 2; mf++) afr[mf] = *(const bf16x8*)&lA[(w*32 + mf*16 + r) * 72 + kc];
      #pragma unroll
      for (int nf = 0; nf < 2; nf++) {
        int row = nf*16 + r;
        int cb = (kc * 2) ^ ((row & 7) << 4);
        bfr[nf] = *(const bf16x8*)((const char*)lB + row * 128 + cb);
      }
      #pragma unroll
      for (int mf = 0; mf < 2; mf++)
        #pragma unroll
        for (int nf = 0; nf < 2; nf++)
          acc[mf][nf] = __builtin_amdgcn_mfma_f32_16x16x32_bf16(afr[mf], bfr[nf], acc[mf][nf], 0, 0, 0);
    }
  }
  int cr = (lane >> 4) * 4, cc = lane & 15;
  #pragma unroll
  for (int mf = 0; mf < 2; mf++)
    #pragma unroll
    for (int nf = 0; nf < 2; nf++)
      #pragma unroll
      for (int qq = 0; qq < 4; qq++) {
        int i   = m0 + w*32 + mf*16 + cr + qq;
        int col = head * 32 + nf*16 + cc;
        atomicAdd(&out[(size_t)i * 256 + col], acc[mf][nf][qq]);
      }
}

// ---------------------------------------------------------------------------
// Small 64x64-tile NT GEMM: C[M,N] = A[M,K] * B[N,K]^T, 4 waves (2x2), bf16 MFMA
template<int CONVA, int OUTBF>
__global__ __launch_bounds__(256) void gemm_small(const void* __restrict__ Ap,
                                                  const unsigned short* __restrict__ B,
                                                  void* __restrict__ Cp,
                                                  int M, int N, int K, int nMtiles) {
  __shared__ __align__(16) unsigned short lA[64 * 72];
  __shared__ __align__(16) unsigned short lB[64 * 72];
  int bid = blockIdx.x;
  int mtile = bid % nMtiles, ntile = bid / nMtiles;
  int m0 = mtile * 64, n0 = ntile * 64;
  int t = threadIdx.x, w = t >> 6, lane = t & 63;
  int wr = w >> 1, wc = w & 1;
  f32x4 acc[2][2] = {};
  for (int kt = 0; kt < K; kt += 64) {
    __syncthreads();
    #pragma unroll
    for (int rep = 0; rep < 2; rep++) {
      int sc = rep * 256 + t;
      int row = sc >> 3, c8 = sc & 7;
      if (CONVA) {
        const float* src = (const float*)Ap + (size_t)(m0 + row) * K + kt + c8 * 8;
        float4 u0 = *(const float4*)src, u1 = *(const float4*)(src + 4);
        s16x8 o;
        o[0]=f2bf(u0.x); o[1]=f2bf(u0.y); o[2]=f2bf(u0.z); o[3]=f2bf(u0.w);
        o[4]=f2bf(u1.x); o[5]=f2bf(u1.y); o[6]=f2bf(u1.z); o[7]=f2bf(u1.w);
        *(s16x8*)&lA[row * 72 + c8 * 8] = o;
      } else {
        *(s16x8*)&lA[row * 72 + c8 * 8] =
            *(const s16x8*)((const unsigned short*)Ap + (size_t)(m0 + row) * K + kt + c8 * 8);
      }
      *(s16x8*)&lB[row * 72 + c8 * 8] = *(const s16x8*)(B + (size_t)(n0 + row) * K + kt + c8 * 8);
    }
    __syncthreads();
    #pragma unroll
    for (int kk = 0; kk < 2; kk++) {
      int r = lane & 15, kc = kk * 32 + (lane >> 4) * 8;
      bf16x8 afr[2], bfr[2];
      #pragma unroll
      for (int mf = 0; mf < 2; mf++) afr[mf] = *(const bf16x8*)&lA[(wr*32 + mf*16 + r) * 72 + kc];
      #pragma unroll
      for (int nf = 0; nf < 2; nf++) bfr[nf] = *(const bf16x8*)&lB[(wc*32 + nf*16 + r) * 72 + kc];
      #pragma unroll
      for (int mf = 0; mf < 2; mf++)
        #pragma unroll
        for (int nf = 0; nf < 2; nf++)
          acc[mf][nf] = __builtin_amdgcn_mfma_f32_16x16x32_bf16(afr[mf], bfr[nf], acc[mf][nf], 0, 0, 0);
    }
  }
  int cr = (lane >> 4) * 4, cc = lane & 15;
  #pragma unroll
  for (int mf = 0; mf < 2; mf++)
    #pragma unroll
    for (int nf = 0; nf < 2; nf++)
      #pragma unroll
      for (int qq = 0; qq < 4; qq++) {
        int row = m0 + wr*32 + mf*16 + cr + qq;
        int col = n0 + wc*32 + nf*16 + cc;
        float vv = acc[mf][nf][qq];
        if (OUTBF) ((unsigned short*)Cp)[(size_t)row * N + col] = f2bf(vv);
        else       ((float*)Cp)[(size_t)row * N + col] = vv;
      }
}

// ---------------------------------------------------------------------------
// softmax over rows of logits[n*512+i][l], causal l<=i, scale 1/sqrt(512)
__global__ __launch_bounds__(256) void k4b_softmax(const float* __restrict__ logits,
                                                   unsigned short* __restrict__ probs) {
  __shared__ float red[4];
  __shared__ float red2[4];
  int m = blockIdx.x, t = threadIdx.x;
  int i = m & (SEQ - 1);
  const float scale = 0.04419417382415922f;   // 1/sqrt(512)
  const float NEG = -1e30f;
  float v0 = (t       <= i) ? logits[(size_t)m * SEQ + t      ] * scale : NEG;
  float v1 = (t + 256 <= i) ? logits[(size_t)m * SEQ + t + 256] * scale : NEG;
  float mx = fmaxf(v0, v1);
  #pragma unroll
  for (int off = 32; off; off >>= 1) mx = fmaxf(mx, __shfl_xor(mx, off));
  int w = t >> 6, lane = t & 63;
  if (lane == 0) red[w] = mx;
  __syncthreads();
  mx = fmaxf(fmaxf(red[0], red[1]), fmaxf(red[2], red[3]));
  float e0 = (t       <= i) ? __expf(v0 - mx) : 0.f;
  float e1 = (t + 256 <= i) ? __expf(v1 - mx) : 0.f;
  float s = e0 + e1;
  #pragma unroll
  for (int off = 32; off; off >>= 1) s += __shfl_xor(s, off);
  if (lane == 0) red2[w] = s;
  __syncthreads();
  s = red2[0] + red2[1] + red2[2] + red2[3];
  float inv = 1.f / s;
  probs[(size_t)m * SEQ + t]       = f2bf(e0 * inv);
  probs[(size_t)m * SEQ + t + 256] = f2bf(e1 * inv);
}

// ---------------------------------------------------------------------------
extern "C" void kernel_launch(void* const* d_in, const int* in_sizes, int n_in,
                              void* d_out, int out_size, void* d_ws, size_t ws_size,
                              hipStream_t stream) {
  (void)in_sizes; (void)n_in; (void)out_size; (void)ws_size;
  const float* q  = (const float*)d_in[0];
  const float* k  = (const float*)d_in[1];
  const float* v  = (const float*)d_in[2];
  const float* Wq = (const float*)d_in[3];
  const float* Wk = (const float*)d_in[4];
  const float* Wv = (const float*)d_in[5];
  float* out = (float*)d_out;

  char* ws = (char*)d_ws;
  size_t off = 0;
  auto alloc = [&](size_t bytes) -> void* {
    void* p = ws + off; off += (bytes + 255) & ~(size_t)255; return p;
  };
  float*          qpf    = (float*)         alloc((size_t)SEQ * DM * 4);
  unsigned short* kbf    = (unsigned short*)alloc((size_t)SEQ * DM * 2);
  unsigned short* vT     = (unsigned short*)alloc((size_t)DM * SEQ * 2);
  unsigned short* Wkb    = (unsigned short*)alloc((size_t)DM * DM * DM * 2);  // 32 MB
  unsigned short* Wvb    = (unsigned short*)alloc((size_t)DM * DM * DM * 2);  // 32 MB
  float*          af     = (float*)         alloc((size_t)NH * SEQ * DM * 4); // 4 MB
  float*          logits = (float*)         alloc((size_t)NH * SEQ * SEQ * 4);
  unsigned short* probs  = (unsigned short*)alloc((size_t)NH * SEQ * SEQ * 2);
  unsigned short* wbf    = (unsigned short*)alloc((size_t)NH * SEQ * DM * 2);

  hipMemsetAsync(af, 0, (size_t)NH * SEQ * DM * 4, stream);
  hipMemsetAsync(out, 0, (size_t)SEQ * DM * 4, stream);

  kconv<<<2048, 256, 0, stream>>>(Wk, Wkb);
  kconv<<<2048, 256, 0, stream>>>(Wv, Wvb);
  k0_convert<<<64, 256, 0, stream>>>(k, v, kbf, vT);
  k1_qproj<<<SEQ, 256, 0, stream>>>(q, Wq, qpf);
  // a[n,i,b]: fused qp⊗qp x Wk hyper-GEMM (17.2 GFLOP), K-split 8, atomics
  ka_gemm<<<512, 256, 0, stream>>>(Wkb, qpf, af);
  // logits = a @ kbf^T : M=4096, N=512, K=256
  gemm_small<1,0><<<512, 256, 0, stream>>>((const void*)af, kbf, (void*)logits, NH*SEQ, SEQ, DM, 64);
  k4b_softmax<<<NH*SEQ, 256, 0, stream>>>(logits, probs);
  // w = probs @ v : M=4096, N=256, K=512 (B = vT)
  gemm_small<0,1><<<256, 256, 0, stream>>>((const void*)probs, vT, (void*)wbf, NH*SEQ, DM, SEQ, 64);
  // out: fused w⊗qp x Wv hyper-GEMM (17.2 GFLOP), K-split 16, atomics
  ko_gemm<<<512, 256, 0, stream>>>(Wvb, qpf, wbf, out);
}